// Round 10
// baseline (229.565 us; speedup 1.0000x reference)
//
#include <hip/hip_runtime.h>
#include <cstdint>

// B=4, L=2048, H=512, HEADS=8, D=64.
// Only the DIAGONAL of softmax(scores) is consumed:
//   diag_i = exp(s_ii) / sum_j exp(s_ij),
//   s_ij = q_i.k_j + q_i.Wp[2047+j-i (padded)] + Wp_b[2047+j-i]
// Logits in log2 units (q pre-scaled by log2e/8 via prep-scaled Wq, bias by log2e).

typedef unsigned short u16;
typedef __bf16 bf16x8 __attribute__((ext_vector_type(8)));
typedef __bf16 bf16x2 __attribute__((ext_vector_type(2)));
typedef float  f32x16 __attribute__((ext_vector_type(16)));
typedef uint32_t __attribute__((address_space(1))) as1_u32;
typedef uint32_t __attribute__((address_space(3))) as3_u32;

__device__ __forceinline__ u16 f2bf(float f) {
  __bf16 h = (__bf16)f;
  return __builtin_bit_cast(u16, h);
}
__device__ __forceinline__ uint32_t pkbf(float a, float b) {
  bf16x2 v; v[0] = (__bf16)a; v[1] = (__bf16)b;
  return __builtin_bit_cast(uint32_t, v);
}
__device__ __forceinline__ float bf2f(u16 u) {
  return __uint_as_float(((uint32_t)u) << 16);
}
__device__ __forceinline__ float exp2v(float x) {
  float r;
  asm("v_exp_f32 %0, %1" : "=v"(r) : "v"(x));
  return r;
}
__device__ __forceinline__ void gl_lds16(const void* g, void* l) {
  __builtin_amdgcn_global_load_lds((const as1_u32*)g, (as3_u32*)l, 16, 0, 0);
}

// ---------------------------------------------------------------------------
// Prep: fp32 -> bf16 for q_in/k_in/v_in, Wq/Wk/Wv/Wo, Wp (padded to 4096 rows)
// Wq is pre-scaled by log2e/8 so the QKV epilogue needs no multiply.
// ---------------------------------------------------------------------------
__global__ __launch_bounds__(256) void prep_kernel(
    const float* __restrict__ qin, const float* __restrict__ kin, const float* __restrict__ vin,
    const float* __restrict__ wq,  const float* __restrict__ wk,  const float* __restrict__ wv,
    const float* __restrict__ wo,  const float* __restrict__ wp,
    u16* __restrict__ xq, u16* __restrict__ xk, u16* __restrict__ xv,
    u16* __restrict__ bwq, u16* __restrict__ bwk, u16* __restrict__ bwv,
    u16* __restrict__ bwo, u16* __restrict__ bwp) {
  long u = (long)blockIdx.x * 256 + threadIdx.x;
  const float* src; u16* dst; long off; float qs = 1.0f;
  if      (u < 524288L)  { src = qin; dst = xq;  off = u; }
  else if (u < 1048576L) { src = kin; dst = xk;  off = u - 524288L; }
  else if (u < 1572864L) { src = vin; dst = xv;  off = u - 1048576L; }
  else if (u < 1605632L) { src = wq;  dst = bwq; off = u - 1572864L; qs = 0.18033688f; }
  else if (u < 1638400L) { src = wk;  dst = bwk; off = u - 1605632L; }
  else if (u < 1671168L) { src = wv;  dst = bwv; off = u - 1638400L; }
  else if (u < 1703936L) { src = wo;  dst = bwo; off = u - 1671168L; }
  else if (u < 1736696L) { src = wp;  dst = bwp; off = u - 1703936L; }
  else {  // zero-fill Wp pad row 4095
    long o = (u - 1736696L) * 8 + 262080L;
    uint4 z = {0u, 0u, 0u, 0u};
    *(uint4*)(bwp + o) = z;
    return;
  }
  const float4* s4 = (const float4*)(src + off * 8);
  float4 a = s4[0], b = s4[1];
  uint32_t p0 = pkbf(a.x * qs, a.y * qs);
  uint32_t p1 = pkbf(a.z * qs, a.w * qs);
  uint32_t p2 = pkbf(b.x * qs, b.y * qs);
  uint32_t p3 = pkbf(b.z * qs, b.w * qs);
  uint4 o = {p0, p1, p2, p3};
  *(uint4*)(dst + off * 8) = o;
}

// ---------------------------------------------------------------------------
// 64x64-tile GEMM core (C = A @ W^T), 4 waves, each wave one 32x32 quadrant.
// ---------------------------------------------------------------------------
__device__ __forceinline__ void gemm64_core(
    const u16* __restrict__ A, const u16* __restrict__ W, int m0, int n0,
    u16* Al, u16* Bl, int tid, f32x16& acc) {
  const int lane = tid & 63, w = tid >> 6;
  const int wi = w >> 1, wj = w & 1;
  const int l31 = lane & 31, lh = lane >> 5;
  const int r = tid >> 2, ch = tid & 3;
  const int gch = ch ^ ((r >> 1) & 3);
  for (int kb = 0; kb < 16; ++kb) {
    gl_lds16(A + (long)(m0 + r) * 512 + kb * 32 + gch * 8, (char*)Al + w * 64 * 16);
    gl_lds16(W + (long)(n0 + r) * 512 + kb * 32 + gch * 8, (char*)Bl + w * 64 * 16);
    __syncthreads();
    bf16x8 af[2], bfr[2];
#pragma unroll
    for (int ks = 0; ks < 2; ++ks) {
      int c2 = 2 * ks + lh;
      int rA = 32 * wi + l31;
      int rB = 32 * wj + l31;
      af[ks]  = *(const bf16x8*)((char*)Al + (rA * 4 + (c2 ^ ((rA >> 1) & 3))) * 16);
      bfr[ks] = *(const bf16x8*)((char*)Bl + (rB * 4 + (c2 ^ ((rB >> 1) & 3))) * 16);
    }
#pragma unroll
    for (int ks = 0; ks < 2; ++ks)
      acc = __builtin_amdgcn_mfma_f32_32x32x16_bf16(af[ks], bfr[ks], acc, 0, 0, 0);
    __syncthreads();
  }
}

// gemm_bt: final projection, fp32 out row-major. 1024 blocks.
__global__ __launch_bounds__(256, 4) void gemm_bt(
    const u16* __restrict__ A, const u16* __restrict__ W, const float* __restrict__ bias,
    float* __restrict__ ofp) {
  __shared__ u16 Al[64 * 32];
  __shared__ u16 Bl[64 * 32];
  const int tid = threadIdx.x;
  const int lane = tid & 63, w = tid >> 6;
  const int wi = w >> 1, wj = w & 1;
  const int l31 = lane & 31, lh = lane >> 5;
  const int u = (blockIdx.x & 7) * 128 + (blockIdx.x >> 3);
  const int m0 = (u >> 3) * 64, n0 = (u & 7) * 64;

  float bv = bias[n0 + 32 * wj + l31];
  f32x16 acc;
#pragma unroll
  for (int rr = 0; rr < 16; ++rr) acc[rr] = bv;

  gemm64_core(A, W, m0, n0, Al, Bl, tid, acc);

  int n = n0 + 32 * wj + l31;
#pragma unroll
  for (int rr = 0; rr < 16; ++rr) {
    int row = m0 + 32 * wi + (rr & 3) + 8 * (rr >> 2) + 4 * lh;
    ofp[(long)row * 512 + n] = acc[rr];
  }
}

// qkv_gemm: 3072 blocks (3 mats x 1024), bf16 out in (b,h,l,d).
__global__ __launch_bounds__(256, 4) void qkv_gemm(
    const u16* __restrict__ xq, const u16* __restrict__ xk, const u16* __restrict__ xv,
    const u16* __restrict__ wqp, const u16* __restrict__ wkp, const u16* __restrict__ wvp,
    const float* __restrict__ bq, const float* __restrict__ bk, const float* __restrict__ bv,
    u16* __restrict__ oq, u16* __restrict__ ok, u16* __restrict__ ov) {
  __shared__ u16 Al[64 * 32];
  __shared__ u16 Bl[64 * 32];
  const int mat = blockIdx.x >> 10;
  const int t = blockIdx.x & 1023;
  const u16* A = (mat == 0) ? xq : (mat == 1) ? xk : xv;
  const u16* W = (mat == 0) ? wqp : (mat == 1) ? wkp : wvp;
  const float* bias = (mat == 0) ? bq : (mat == 1) ? bk : bv;
  u16* obf = (mat == 0) ? oq : (mat == 1) ? ok : ov;
  const float bsc = (mat == 0) ? 0.18033688f : 1.0f;

  const int tid = threadIdx.x;
  const int lane = tid & 63, w = tid >> 6;
  const int wi = w >> 1, wj = w & 1;
  const int l31 = lane & 31, lh = lane >> 5;
  const int u = (t & 7) * 128 + (t >> 3);
  const int m0 = (u >> 3) * 64, n0 = (u & 7) * 64;

  float bvv = bias[n0 + 32 * wj + l31] * bsc;
  f32x16 acc;
#pragma unroll
  for (int rr = 0; rr < 16; ++rr) acc[rr] = bvv;

  gemm64_core(A, W, m0, n0, Al, Bl, tid, acc);

  int n = n0 + 32 * wj + l31;
  int h = n >> 6, d = n & 63;
#pragma unroll
  for (int rr = 0; rr < 16; ++rr) {
    int row = m0 + 32 * wi + (rr & 3) + 8 * (rr >> 2) + 4 * lh;
    int b = row >> 11, l = row & 2047;
    obf[(((long)(b * 8 + h)) * 2048 + l) * 64 + d] = f2bf(acc[rr]);
  }
}

// ---------------------------------------------------------------------------
// Attention v10 = v9 + full prefetch pipeline + conflict-free ring stride.
// 1024 blocks (b,h, 64-row i-tile); wave w owns cols [512w,512w+512), 16 steps,
// 64 q-rows per wave (sets A/B), barrier-free, skewed wave-private LDS rings.
// Pipeline per step t (steady state):
//   top:   load kf(t+1) [parity buf]; load Wp frags m=t+2 [parity buf]
//   mid:   S-MFMA A,B with kf(t) (prefetched) on accS (gathered last step);
//          diag; exp x32 + rsum
//   tail:  PCOMP-B tile t+2 (frags m=t+1, prev step's buf);
//          PCOMP-A tile t+2 (frags m=t+2, loaded this step top, ~400cyc ago);
//          gather accSA/accSB for step t+1 (reads tiles t+1,t+2 - just written;
//          intra-wave lgkmcnt orders write->read)
// Only cross-step dep: ds_write -> gather -> S-MFMA (short LDS latencies).
// Ring: stride 38 u16 (76 B): bank stride 19 (odd) -> 32 lanes cover all 32
// banks, lh group +14/+2 banks -> wave = 2-way max (free). b32 gather reads
// (stride 38 breaks b64 alignment; 8 x u32, 4B-aligned, ds_read2-mergeable).
// Cell (q, W=wbA+trow) at [u=(trow+q)&127][v=q], row = 38 u16.
// LDS: 8 rings x 128 x 38 x 2B = 77824 B -> 2 blocks/CU; (256,2) -> 256-VGPR
// budget, peak live ~190: no spill expected (guard: WRITE_SIZE ~ 8.2 MB).
// Wp row max = 4095 exactly (zero pad row); bias clamp 4094 (never gathered).
// ---------------------------------------------------------------------------
#define LOADK(T, K0, K1, K2, K3)                                                 \
  do {                                                                           \
    const u16* kp_ = kb + (long)(c0 + 32 * (T) + l31) * 64 + lh * 8;             \
    K0 = *(const bf16x8*)(kp_);                                                  \
    K1 = *(const bf16x8*)(kp_ + 16);                                             \
    K2 = *(const bf16x8*)(kp_ + 32);                                             \
    K3 = *(const bf16x8*)(kp_ + 48);                                             \
  } while (0)

#define LOADNB(M, N0, N1, N2, N3, NV)                                            \
  do {                                                                           \
    int wr_ = wbA + 32 * (M) + l31;                                              \
    const u16* bp_ = wpw + (long)wr_ * 64 + lh * 8;                              \
    N0 = *(const bf16x8*)(bp_);                                                  \
    N1 = *(const bf16x8*)(bp_ + 16);                                             \
    N2 = *(const bf16x8*)(bp_ + 32);                                             \
    N3 = *(const bf16x8*)(bp_ + 48);                                             \
    NV = wpb[wr_ > 4094 ? 4094 : wr_] * 1.44269504f;                             \
  } while (0)

#define PCOMP(RING, G, AQ0, AQ1, AQ2, AQ3, B0, B1, B2, B3, BV)                   \
  do {                                                                           \
    f32x16 accP;                                                                 \
    _Pragma("unroll")                                                            \
    for (int r = 0; r < 16; ++r) accP[r] = (BV);                                 \
    accP = __builtin_amdgcn_mfma_f32_32x32x16_bf16(AQ0, B0, accP, 0, 0, 0);      \
    accP = __builtin_amdgcn_mfma_f32_32x32x16_bf16(AQ1, B1, accP, 0, 0, 0);      \
    accP = __builtin_amdgcn_mfma_f32_32x32x16_bf16(AQ2, B2, accP, 0, 0, 0);      \
    accP = __builtin_amdgcn_mfma_f32_32x32x16_bf16(AQ3, B3, accP, 0, 0, 0);      \
    int bw_ = 32 * (G) + l31 + 4 * lh;                                           \
    _Pragma("unroll")                                                            \
    for (int r = 0; r < 16; ++r) {                                               \
      const int lrr = (r & 3) + 8 * (r >> 2);                                    \
      int uu = (bw_ + lrr) & 127;                                                \
      (RING)[uu * 38 + lrr + 4 * lh] = f2bf(accP[r]);                            \
    }                                                                            \
  } while (0)

#define GATH(RING, T, ACC)                                                       \
  do {                                                                           \
    int u_ = (31 + l31 + 32 * (T)) & 127;                                        \
    const uint32_t* p_ = (const uint32_t*)((RING) + u_ * 38 + 4 * lh);           \
    uint32_t g0 = p_[0], g1 = p_[1], g2 = p_[4],  g3 = p_[5];                    \
    uint32_t g4 = p_[8], g5 = p_[9], g6 = p_[12], g7 = p_[13];                   \
    ACC[0]  = __uint_as_float(g0 << 16); ACC[1]  = __uint_as_float(g0 & 0xffff0000u); \
    ACC[2]  = __uint_as_float(g1 << 16); ACC[3]  = __uint_as_float(g1 & 0xffff0000u); \
    ACC[4]  = __uint_as_float(g2 << 16); ACC[5]  = __uint_as_float(g2 & 0xffff0000u); \
    ACC[6]  = __uint_as_float(g3 << 16); ACC[7]  = __uint_as_float(g3 & 0xffff0000u); \
    ACC[8]  = __uint_as_float(g4 << 16); ACC[9]  = __uint_as_float(g4 & 0xffff0000u); \
    ACC[10] = __uint_as_float(g5 << 16); ACC[11] = __uint_as_float(g5 & 0xffff0000u); \
    ACC[12] = __uint_as_float(g6 << 16); ACC[13] = __uint_as_float(g6 & 0xffff0000u); \
    ACC[14] = __uint_as_float(g7 << 16); ACC[15] = __uint_as_float(g7 & 0xffff0000u); \
  } while (0)

#define ATTN_STEP(T, KC0, KC1, KC2, KC3, KN0, KN1, KN2, KN3,                     \
                  NU0, NU1, NU2, NU3, NUV, NN0, NN1, NN2, NN3, NNV,              \
                  DOK, DOP)                                                      \
  do {                                                                           \
    const int t_ = (T);                                                          \
    if (DOK) { LOADK(t_ + 1, KN0, KN1, KN2, KN3); }                              \
    if (DOP) { LOADNB(t_ + 2, NN0, NN1, NN2, NN3, NNV); }                        \
    accSA = __builtin_amdgcn_mfma_f32_32x32x16_bf16(aqA0, KC0, accSA, 0, 0, 0);  \
    accSA = __builtin_amdgcn_mfma_f32_32x32x16_bf16(aqA1, KC1, accSA, 0, 0, 0);  \
    accSA = __builtin_amdgcn_mfma_f32_32x32x16_bf16(aqA2, KC2, accSA, 0, 0, 0);  \
    accSA = __builtin_amdgcn_mfma_f32_32x32x16_bf16(aqA3, KC3, accSA, 0, 0, 0);  \
    accSB = __builtin_amdgcn_mfma_f32_32x32x16_bf16(aqB0, KC0, accSB, 0, 0, 0);  \
    accSB = __builtin_amdgcn_mfma_f32_32x32x16_bf16(aqB1, KC1, accSB, 0, 0, 0);  \
    accSB = __builtin_amdgcn_mfma_f32_32x32x16_bf16(aqB2, KC2, accSB, 0, 0, 0);  \
    accSB = __builtin_amdgcn_mfma_f32_32x32x16_bf16(aqB3, KC3, accSB, 0, 0, 0);  \
    if (diagw && t_ == tdA) {                                                    \
      _Pragma("unroll")                                                          \
      for (int r = 0; r < 16; ++r) {                                             \
        const int lrr = (r & 3) + 8 * (r >> 2);                                  \
        if (l31 == lrr + 4 * lh) sdiag[lrr + 4 * lh] = accSA[r];                 \
      }                                                                          \
    }                                                                            \
    if (diagw && t_ == tdA + 1) {                                                \
      _Pragma("unroll")                                                          \
      for (int r = 0; r < 16; ++r) {                                             \
        const int lrr = (r & 3) + 8 * (r >> 2);                                  \
        if (l31 == lrr + 4 * lh) sdiag[32 + lrr + 4 * lh] = accSB[r];            \
      }                                                                          \
    }                                                                            \
    _Pragma("unroll")                                                            \
    for (int r = 0; r < 16; ++r) rsum[r] += exp2v(accSA[r]);                     \
    _Pragma("unroll")                                                            \
    for (int r = 0; r < 16; ++r) rsum[16 + r] += exp2v(accSB[r]);                \
    if (DOP) {                                                                   \
      PCOMP(ringB, t_ + 2, aqB0, aqB1, aqB2, aqB3, NU0, NU1, NU2, NU3, NUV);     \
      PCOMP(ringA, t_ + 2, aqA0, aqA1, aqA2, aqA3, NN0, NN1, NN2, NN3, NNV);     \
      GATH(ringA, t_ + 1, accSA);                                                \
      GATH(ringB, t_ + 1, accSB);                                                \
    }                                                                            \
  } while (0)

__global__ __launch_bounds__(256, 2) void attn_kernel(
    const u16* __restrict__ qw, const u16* __restrict__ kw, const u16* __restrict__ vw,
    const u16* __restrict__ wpw, const float* __restrict__ wpb, u16* __restrict__ outp) {
  __shared__ u16 Pl[8 * 128 * 38];   // 77824 B: per wave 2 skewed rings (A,B)
  __shared__ float sdiag[64];
  __shared__ float rssum[64 * 4];
  __shared__ float attw[64];

  const int tid = threadIdx.x, lane = tid & 63, w = tid >> 6;
  // XCD swizzle: 1024 blocks; XCD x gets bh in {x, x+8, x+16, x+24}.
  const int sbi = blockIdx.x;
  const int x = sbi & 7, g = sbi >> 3;          // g in 0..127
  const int bh = x + 8 * (g >> 5);
  const int it = g & 31;
  const int i0 = it * 64;
  const u16* qb = qw + (long)bh * 2048 * 64;
  const u16* kb = kw + (long)bh * 2048 * 64;
  const u16* vb = vw + (long)bh * 2048 * 64;

  const int l31 = lane & 31, lh = lane >> 5;
  const int c0 = w << 9;                        // wave's column base
  const int wbA = 2016 + c0 - i0;               // A window base (B = A - 32)
  const bool diagw = (w == (it >> 3));
  const int tdA = 2 * (it & 7);

  u16* ringA = Pl + w * 9728;                   // 128*38 u16 each
  u16* ringB = ringA + 4864;

  // A-fragments: q rows i0+l31 (set A) and i0+32+l31 (set B), full K=64
  bf16x8 aqA0, aqA1, aqA2, aqA3, aqB0, aqB1, aqB2, aqB3;
  {
    const u16* pA = qb + (long)(i0 + l31) * 64 + lh * 8;
    aqA0 = *(const bf16x8*)(pA);
    aqA1 = *(const bf16x8*)(pA + 16);
    aqA2 = *(const bf16x8*)(pA + 32);
    aqA3 = *(const bf16x8*)(pA + 48);
    const u16* pB = pA + 32 * 64;
    aqB0 = *(const bf16x8*)(pB);
    aqB1 = *(const bf16x8*)(pB + 16);
    aqB2 = *(const bf16x8*)(pB + 32);
    aqB3 = *(const bf16x8*)(pB + 48);
  }

  float rsum[32];
#pragma unroll
  for (int r = 0; r < 32; ++r) rsum[r] = 0.f;

  // pipeline state
  bf16x8 kfA0, kfA1, kfA2, kfA3, kfB0, kfB1, kfB2, kfB3;
  bf16x8 nb00, nb01, nb02, nb03, nb10, nb11, nb12, nb13;
  float nbv0, nbv1;
  f32x16 accSA, accSB;

  // prologue: rings tiles 0,1; nb1 = Wp m=1; kfA = K(0); initial gathers.
  {
    bf16x8 t0, t1, t2, t3; float tv;
    LOADNB(-1, t0, t1, t2, t3, tv);
    PCOMP(ringB, 0, aqB0, aqB1, aqB2, aqB3, t0, t1, t2, t3, tv);
    LOADNB(0, t0, t1, t2, t3, tv);
    PCOMP(ringA, 0, aqA0, aqA1, aqA2, aqA3, t0, t1, t2, t3, tv);
    PCOMP(ringB, 1, aqB0, aqB1, aqB2, aqB3, t0, t1, t2, t3, tv);
    LOADNB(1, nb10, nb11, nb12, nb13, nbv1);
    PCOMP(ringA, 1, aqA0, aqA1, aqA2, aqA3, nb10, nb11, nb12, nb13, nbv1);
    LOADK(0, kfA0, kfA1, kfA2, kfA3);
    GATH(ringA, 0, accSA);
    GATH(ringB, 0, accSB);
  }

  // main loop: 16 steps; even uses kfA/nb1, loads kfB/nb0; odd swaps.
  for (int tt = 0; tt < 14; tt += 2) {
    ATTN_STEP(tt,     kfA0, kfA1, kfA2, kfA3, kfB0, kfB1, kfB2, kfB3,
              nb10, nb11, nb12, nb13, nbv1, nb00, nb01, nb02, nb03, nbv0,
              true, true);
    ATTN_STEP(tt + 1, kfB0, kfB1, kfB2, kfB3, kfA0, kfA1, kfA2, kfA3,
              nb00, nb01, nb02, nb03, nbv0, nb10, nb11, nb12, nb13, nbv1,
              true, true);
  }
  ATTN_STEP(14, kfA0, kfA1, kfA2, kfA3, kfB0, kfB1, kfB2, kfB3,
            nb10, nb11, nb12, nb13, nbv1, nb00, nb01, nb02, nb03, nbv0,
            true, true);
  ATTN_STEP(15, kfB0, kfB1, kfB2, kfB3, kfA0, kfA1, kfA2, kfA3,
            nb00, nb01, nb02, nb03, nbv0, nb10, nb11, nb12, nb13, nbv1,
            false, false);

  // reduce row partials across the 32 col-lanes
#pragma unroll
  for (int r = 0; r < 32; ++r) {
    float v = rsum[r];
    v += __shfl_xor(v, 1);
    v += __shfl_xor(v, 2);
    v += __shfl_xor(v, 4);
    v += __shfl_xor(v, 8);
    v += __shfl_xor(v, 16);
    rsum[r] = v;
  }
  if (l31 == 0) {
#pragma unroll
    for (int r = 0; r < 16; ++r) {
      int lr = (r & 3) + 8 * (r >> 2) + 4 * lh;
      rssum[lr * 4 + w] = rsum[r];
      rssum[(32 + lr) * 4 + w] = rsum[16 + r];
    }
  }
  __syncthreads();
  if (tid < 64) {
    float S = rssum[tid * 4] + rssum[tid * 4 + 1] + rssum[tid * 4 + 2] + rssum[tid * 4 + 3];
    attw[tid] = exp2v(sdiag[tid]) / S;
  }
  __syncthreads();
  // out_pre[b*2048 + i][h*64 + d] = diag * v   (bf16)
  {
    int r = tid >> 2, dd = (tid & 3) * 16;
    float a = attw[r];
    int b = bh >> 3, h = bh & 7;
    const u16* vp = vb + (long)(i0 + r) * 64 + dd;
    u16* op = outp + ((long)(b * 2048 + i0 + r)) * 512 + h * 64 + dd;
    uint4 v0 = *(const uint4*)vp;
    uint4 v1 = *(const uint4*)(vp + 8);
    uint32_t vin[8] = {v0.x, v0.y, v0.z, v0.w, v1.x, v1.y, v1.z, v1.w};
    uint32_t vout[8];
#pragma unroll
    for (int e = 0; e < 8; ++e) {
      float lo = bf2f((u16)(vin[e] & 0xffffu)) * a;
      float hi = bf2f((u16)(vin[e] >> 16)) * a;
      vout[e] = pkbf(lo, hi);
    }
    uint4 o0 = {vout[0], vout[1], vout[2], vout[3]};
    uint4 o1 = {vout[4], vout[5], vout[6], vout[7]};
    *(uint4*)op = o0;
    *(uint4*)(op + 8) = o1;
  }
}

// ---------------------------------------------------------------------------
extern "C" void kernel_launch(void* const* d_in, const int* in_sizes, int n_in,
                              void* d_out, int out_size, void* d_ws, size_t ws_size,
                              hipStream_t stream) {
  (void)in_sizes; (void)n_in; (void)out_size; (void)ws_size;
  const float* q_in = (const float*)d_in[0];
  const float* k_in = (const float*)d_in[1];
  const float* v_in = (const float*)d_in[2];
  const float* Wq_w = (const float*)d_in[3];
  const float* Wq_b = (const float*)d_in[4];
  const float* Wk_w = (const float*)d_in[5];
  const float* Wk_b = (const float*)d_in[6];
  const float* Wv_w = (const float*)d_in[7];
  const float* Wv_b = (const float*)d_in[8];
  const float* Wo_w = (const float*)d_in[9];
  const float* Wo_b = (const float*)d_in[10];
  const float* Wp_w = (const float*)d_in[11];
  const float* Wp_b = (const float*)d_in[12];

  char* ws = (char*)d_ws;
  u16* xq    = (u16*)(ws + 0);         // 8 MB  bf16 q_in
  u16* xk    = (u16*)(ws + 8388608);   // 8 MB
  u16* xv    = (u16*)(ws + 16777216);  // 8 MB
  u16* wq    = (u16*)(ws + 25165824);  // 512 KB each
  u16* wk    = (u16*)(ws + 25690112);
  u16* wv    = (u16*)(ws + 26214400);
  u16* wo    = (u16*)(ws + 26738688);
  u16* wp    = (u16*)(ws + 27262976);  // 4096x64 bf16 (row 4095 zero)
  u16* q_ws  = (u16*)(ws + 27787264);  // (b,h,l,d) bf16, pre-scaled log2e/8
  u16* k_ws  = (u16*)(ws + 36175872);
  u16* v_ws  = (u16*)(ws + 44564480);
  u16* opre  = (u16*)(ws + 52953088);  // (b*l, h*d) bf16 diag-scaled v

  prep_kernel<<<6784, 256, 0, stream>>>(q_in, k_in, v_in, Wq_w, Wk_w, Wv_w, Wo_w, Wp_w,
                                        xq, xk, xv, wq, wk, wv, wo, wp);
  qkv_gemm<<<3072, 256, 0, stream>>>(xq, xk, xv, wq, wk, wv, Wq_b, Wk_b, Wv_b,
                                     q_ws, k_ws, v_ws);
  attn_kernel<<<1024, 256, 0, stream>>>(q_ws, k_ws, v_ws, wp, Wp_b, opre);
  gemm_bt<<<1024, 256, 0, stream>>>(opre, wo, Wo_b, (float*)d_out);
}